// Round 1
// baseline (88.698 us; speedup 1.0000x reference)
//
#include <hip/hip_runtime.h>

#define B_   4
#define H_   64
#define W_   64
#define C_   256
#define HO_  58
#define WO_  58
#define TI_  29     // 2-row tiles
#define TJ_  29     // 2-col tiles
#define GRID (B_ * TI_ * TJ_)   // 3364 = 8*420 + 4

// 32-lane sum via DPP on the VALU pipe (no DS traffic). Result in lanes 31 and 63.
template <int CTRL>
__device__ __forceinline__ float dpp_add(float p) {
    int t = __builtin_amdgcn_update_dpp(0, __builtin_bit_cast(int, p),
                                        CTRL, 0xF, 0xF, true);  // bound_ctrl: OOB -> 0
    return p + __builtin_bit_cast(float, t);
}
__device__ __forceinline__ float reduce32_dpp(float p) {
    p = dpp_add<0x111>(p);   // row_shr:1
    p = dpp_add<0x112>(p);   // row_shr:2
    p = dpp_add<0x114>(p);   // row_shr:4
    p = dpp_add<0x118>(p);   // row_shr:8  -> lane15/31/47/63 hold 16-lane sums
    p = dpp_add<0x142>(p);   // row_bcast:15 -> lanes 31,63 hold 32-lane sums
    return p;
}

__device__ __forceinline__ float dot8(const float4& k0, const float4& k1,
                                      const float4& q0, const float4& q1) {
    float s = k0.x * q0.x;
    s = fmaf(k0.y, q0.y, s); s = fmaf(k0.z, q0.z, s); s = fmaf(k0.w, q0.w, s);
    s = fmaf(k1.x, q1.x, s); s = fmaf(k1.y, q1.y, s); s = fmaf(k1.z, q1.z, s);
    s = fmaf(k1.w, q1.w, s);
    return s;
}

__global__ __launch_bounds__(256, 4) void convnd_attn_kernel(const float* __restrict__ X,
                                                             float* __restrict__ out) {
    __shared__ float sS[4][64];                     // scores   [px][cell]
    __shared__ float sW[4][64];                     // weights  [px][cell]
    __shared__ __align__(16) float pacc[4][8][C_];  // 32 KiB: [px][slot][ch]

    // Bijective XCD-contiguous swizzle (GRID % 8 == 4): xcd<4 slabs of 421, else 420.
    const int xcd = blockIdx.x & 7;
    const int bt  = blockIdx.x >> 3;
    const int sp  = (xcd < 4) ? (xcd * 421 + bt) : (4 * 421 + (xcd - 4) * 420 + bt);
    const int tj  = sp % TJ_;
    const int tmp = sp / TJ_;
    const int ti  = tmp % TI_;
    const int b   = tmp / TI_;
    const int i0  = 2 * ti;
    const int j0  = 2 * tj;

    const int tid  = threadIdx.x;
    const int wave = tid >> 6;
    const int lane = tid & 63;
    const int g    = lane >> 5;       // which of 2 concurrent cells per wave
    const int sub  = lane & 31;       // 32 lanes per cell, 8 channels each
    const int slot = wave * 2 + g;    // dj column of the 8x8 union, 0..7
    const int co   = 8 * sub;

    const float* base = X + (size_t)b * (H_ * W_ * C_);

    // ---- Load the 8x8 union window: this thread holds column `slot`, all 8 rows.
    float4 kv[8][2];
    #pragma unroll
    for (int r = 0; r < 8; ++r) {
        const float* kp = base + ((i0 + r) * W_ + (j0 + slot)) * C_ + co;
        kv[r][0] = *(const float4*)(kp);
        kv[r][1] = *(const float4*)(kp + 4);
    }

    // ---- Queries for the 4 pixels (their window centers), pre-scaled by 1/16.
    float4 q[4][2];
    #pragma unroll
    for (int p = 0; p < 4; ++p) {
        const int a = p >> 1, c = p & 1;
        const float* qp = base + ((i0 + a + 3) * W_ + (j0 + c + 3)) * C_ + co;
        float4 q0 = *(const float4*)(qp);
        float4 q1 = *(const float4*)(qp + 4);
        q0.x *= 0.0625f; q0.y *= 0.0625f; q0.z *= 0.0625f; q0.w *= 0.0625f;
        q1.x *= 0.0625f; q1.y *= 0.0625f; q1.z *= 0.0625f; q1.w *= 0.0625f;
        q[p][0] = q0; q[p][1] = q1;
    }

    // ---- Dots: 64 cells x 4 px; reduce 32 lanes on the VALU via DPP.
    #pragma unroll
    for (int r = 0; r < 8; ++r) {
        #pragma unroll
        for (int p = 0; p < 4; ++p) {
            float s = dot8(kv[r][0], kv[r][1], q[p][0], q[p][1]);
            s = reduce32_dpp(s);
            if (sub == 31) sS[p][r * 8 + slot] = s;   // lanes 31 (g=0) and 63 (g=1)
        }
    }
    __syncthreads();

    // ---- Softmax: wave w owns pixel w; lane = cell. Scores ~N(0,1): no max-sub.
    {
        const int p  = wave;
        const int a  = p >> 1, c = p & 1;
        const int di = lane >> 3, dj = lane & 7;
        const bool valid = (di >= a) & (di <= a + 6) & (dj >= c) & (dj <= c + 6)
                           & !((di == a + 3) & (dj == c + 3));   // skip center
        const float e = valid ? __expf(sS[p][lane]) : 0.f;
        float ts = e;
        #pragma unroll
        for (int m = 32; m; m >>= 1) ts += __shfl_xor(ts, m, 64);
        sW[p][lane] = e / ts;                          // invalid cells -> weight 0
    }
    __syncthreads();

    // ---- Weighted value accumulation from registers.
    float4 acc[4][2];
    #pragma unroll
    for (int p = 0; p < 4; ++p) {
        acc[p][0] = make_float4(0.f, 0.f, 0.f, 0.f);
        acc[p][1] = make_float4(0.f, 0.f, 0.f, 0.f);
    }
    #pragma unroll
    for (int r = 0; r < 8; ++r) {
        #pragma unroll
        for (int p = 0; p < 4; ++p) {
            const float w = sW[p][r * 8 + slot];       // 32-lane broadcast reads
            acc[p][0].x = fmaf(w, kv[r][0].x, acc[p][0].x);
            acc[p][0].y = fmaf(w, kv[r][0].y, acc[p][0].y);
            acc[p][0].z = fmaf(w, kv[r][0].z, acc[p][0].z);
            acc[p][0].w = fmaf(w, kv[r][0].w, acc[p][0].w);
            acc[p][1].x = fmaf(w, kv[r][1].x, acc[p][1].x);
            acc[p][1].y = fmaf(w, kv[r][1].y, acc[p][1].y);
            acc[p][1].z = fmaf(w, kv[r][1].z, acc[p][1].z);
            acc[p][1].w = fmaf(w, kv[r][1].w, acc[p][1].w);
        }
    }
    #pragma unroll
    for (int p = 0; p < 4; ++p) {
        *(float4*)&pacc[p][slot][co]     = acc[p][0];
        *(float4*)&pacc[p][slot][co + 4] = acc[p][1];
    }
    __syncthreads();

    // ---- Final: thread = channel; sum 8 column-partials per pixel; coalesced stores.
    #pragma unroll
    for (int p = 0; p < 4; ++p) {
        float s = 0.f;
        #pragma unroll
        for (int sl = 0; sl < 8; ++sl) s += pacc[p][sl][tid];
        const int a = p >> 1, c = p & 1;
        out[(((size_t)b * HO_ + (i0 + a)) * WO_ + (j0 + c)) * C_ + tid] = s;
    }
}

extern "C" void kernel_launch(void* const* d_in, const int* in_sizes, int n_in,
                              void* d_out, int out_size, void* d_ws, size_t ws_size,
                              hipStream_t stream) {
    const float* X = (const float*)d_in[0];
    float* outp    = (float*)d_out;
    hipLaunchKernelGGL(convnd_attn_kernel,
                       dim3(GRID), dim3(256), 0, stream, X, outp);
}